// Round 1
// baseline (105.657 us; speedup 1.0000x reference)
//
#include <hip/hip_runtime.h>
#include <math.h>

// Problem geometry
#define N_IMG   48          // B*C = 8*6
#define IMG_W   512
#define IMG_H   512
#define IMG_HW  (IMG_W*IMG_H)
#define OUT_W   506         // 512 - 6 (VALID 7x7)
#define OUT_H   506
#define BAND_H  46          // output rows per band; 46*11 = 506
#define N_BANDS 11
#define K1C     0.01f
#define K2C     0.03f

// ws layout:
//   double wsd[0]     = sum |diff|
//   double wsd[1]     = sum diff^2
//   double wsd[2..49] = per-image SSIM sum
//   unsigned wsu[0..47]  (at byte offset 400) = per-image min (ordered-uint map)
//   unsigned wsu[48..95]                      = per-image max (ordered-uint map)

__device__ __forceinline__ unsigned fmap(float f) {
  unsigned u = __float_as_uint(f);
  return (u & 0x80000000u) ? ~u : (u | 0x80000000u);
}
__device__ __forceinline__ float funmap(unsigned u) {
  return (u & 0x80000000u) ? __uint_as_float(u & 0x7FFFFFFFu)
                           : __uint_as_float(~u);
}

__global__ void init_ws(double* wsd, unsigned* wsu) {
  int t = threadIdx.x;
  if (t < 50) wsd[t] = 0.0;
  if (t < 48) { wsu[t] = 0xFFFFFFFFu; wsu[48 + t] = 0u; }
}

// Pass 1: per-image min/max of y_true*mask, global sum|diff| and sum diff^2.
// 16 blocks per image, 256 threads, float4 loads (16 per thread).
__global__ __launch_bounds__(256) void stat_kernel(
    const float4* __restrict__ p4, const float4* __restrict__ t4,
    const float4* __restrict__ m4, double* __restrict__ wsd,
    unsigned* __restrict__ wsu) {
  const int img = blockIdx.x >> 4;
  const int chunk = blockIdx.x & 15;
  const size_t base = (size_t)img * (IMG_HW / 4) + (size_t)chunk * (IMG_HW / 64);
  const int t = threadIdx.x;

  float s1 = 0.f, s2 = 0.f, mn = INFINITY, mx = -INFINITY;
#pragma unroll 4
  for (int k = 0; k < 16; ++k) {
    size_t idx = base + (size_t)k * 256 + t;
    float4 a = p4[idx], b = t4[idx], m = m4[idx];
    {
      float d = (a.x - b.x) * m.x, v = b.x * m.x;
      s1 += fabsf(d); s2 = fmaf(d, d, s2);
      mn = fminf(mn, v); mx = fmaxf(mx, v);
    }
    {
      float d = (a.y - b.y) * m.y, v = b.y * m.y;
      s1 += fabsf(d); s2 = fmaf(d, d, s2);
      mn = fminf(mn, v); mx = fmaxf(mx, v);
    }
    {
      float d = (a.z - b.z) * m.z, v = b.z * m.z;
      s1 += fabsf(d); s2 = fmaf(d, d, s2);
      mn = fminf(mn, v); mx = fmaxf(mx, v);
    }
    {
      float d = (a.w - b.w) * m.w, v = b.w * m.w;
      s1 += fabsf(d); s2 = fmaf(d, d, s2);
      mn = fminf(mn, v); mx = fmaxf(mx, v);
    }
  }

  // wave64 reduce
#pragma unroll
  for (int off = 32; off; off >>= 1) {
    s1 += __shfl_down(s1, off);
    s2 += __shfl_down(s2, off);
    mn = fminf(mn, __shfl_down(mn, off));
    mx = fmaxf(mx, __shfl_down(mx, off));
  }
  __shared__ float r1[4], r2[4], rmn[4], rmx[4];
  int wave = t >> 6, lane = t & 63;
  if (lane == 0) { r1[wave] = s1; r2[wave] = s2; rmn[wave] = mn; rmx[wave] = mx; }
  __syncthreads();
  if (t == 0) {
    float S1 = 0.f, S2 = 0.f, MN = INFINITY, MX = -INFINITY;
#pragma unroll
    for (int w = 0; w < 4; ++w) {
      S1 += r1[w]; S2 += r2[w];
      MN = fminf(MN, rmn[w]); MX = fmaxf(MX, rmx[w]);
    }
    atomicAdd(&wsd[0], (double)S1);
    atomicAdd(&wsd[1], (double)S2);
    atomicMin(&wsu[img], fmap(MN));
    atomicMax(&wsu[48 + img], fmap(MX));
  }
}

// Pass 2: SSIM over 48 images, one block per (image, band of 46 output rows).
// Thread = output column. Separable 7x7 box sums: horizontal sums from an
// LDS-staged row (double-buffered, 1 barrier/row), vertical running sums in a
// statically-indexed 6-deep register ring.
__global__ __launch_bounds__(512) void ssim_kernel(
    const float* __restrict__ yp, const float* __restrict__ yt,
    const float* __restrict__ mk, double* __restrict__ wsd,
    const unsigned* __restrict__ wsu) {
  const int img = blockIdx.x / N_BANDS;
  const int band = blockIdx.x % N_BANDS;
  const int r0 = band * BAND_H;                   // first output row of band
  const size_t ibase = (size_t)img * IMG_HW;
  const size_t rowbase = ibase + (size_t)r0 * IMG_W;
  const int c = threadIdx.x;                      // 0..511

  // per-image constants
  const float d = funmap(wsu[48 + img]) - funmap(wsu[img]);
  const float C1 = (K1C * d) * (K1C * d);
  const float C2 = (K2C * d) * (K2C * d);

  __shared__ float lx[2][IMG_W];
  __shared__ float ly[2][IMG_W];

  // register ring of the last 6 rows' horizontal sums (all statically indexed)
  float rx[6] = {0,0,0,0,0,0}, ry[6] = {0,0,0,0,0,0};
  float rxx[6] = {0,0,0,0,0,0}, ryy[6] = {0,0,0,0,0,0}, rxy[6] = {0,0,0,0,0,0};
  float vx_ = 0.f, vy_ = 0.f, vxx = 0.f, vyy = 0.f, vxy = 0.f;
  float acc = 0.f;

  // stage input row r0 into buffer 0
  {
    size_t off = rowbase + c;
    float pv = yp[off], tv = yt[off], mv = mk[off];
    lx[0][c] = pv * mv; ly[0][c] = tv * mv;
  }
  __syncthreads();

  const float i49 = 1.0f / 49.0f, i48 = 1.0f / 48.0f;

  // 52 input rows per band: 6 warm-up + 46 producing output rows r0..r0+45
  for (int i = 0; i < BAND_H + 6; ++i) {
    const int cur = i & 1;

    // issue next row's global loads early (hide latency under compute)
    float nx = 0.f, ny = 0.f;
    if (i < BAND_H + 5) {
      size_t off = rowbase + (size_t)(i + 1) * IMG_W + c;
      float pv = yp[off], tv = yt[off], mv = mk[off];
      nx = pv * mv; ny = tv * mv;
    }

    // horizontal 7-sums for this input row
    float hx = 0.f, hy = 0.f, hxx = 0.f, hyy = 0.f, hxy = 0.f;
    if (c < OUT_W) {
#pragma unroll
      for (int j = 0; j < 7; ++j) {
        float xv = lx[cur][c + j], yv = ly[cur][c + j];
        hx += xv; hy += yv;
        hxx = fmaf(xv, xv, hxx);
        hyy = fmaf(yv, yv, hyy);
        hxy = fmaf(xv, yv, hxy);
      }
    }

    if (i >= 6) {
      // 7-row window sums = running 6-row sums + new row
      float sx = vx_ + hx, sy = vy_ + hy;
      float sxx = vxx + hxx, syy = vyy + hyy, sxy = vxy + hxy;
      if (c < OUT_W) {
        float ux = sx * i49, uy = sy * i49;
        float vxv = (sxx - sx * sx * i49) * i48;
        float vyv = (syy - sy * sy * i49) * i48;
        float vxyv = (sxy - sx * sy * i49) * i48;
        float A1 = 2.f * ux * uy + C1;
        float A2 = 2.f * vxyv + C2;
        float B1 = ux * ux + uy * uy + C1;
        float B2 = vxv + vyv + C2;
        acc += (A1 * A2) / (B1 * B2);
      }
      // slide window: drop oldest row (ring[0]), add new
      vx_ += hx - rx[0]; vy_ += hy - ry[0];
      vxx += hxx - rxx[0]; vyy += hyy - ryy[0]; vxy += hxy - rxy[0];
    } else {
      vx_ += hx; vy_ += hy; vxx += hxx; vyy += hyy; vxy += hxy;
    }
    // shift ring (static indices -> stays in registers)
#pragma unroll
    for (int j = 0; j < 5; ++j) {
      rx[j] = rx[j + 1]; ry[j] = ry[j + 1];
      rxx[j] = rxx[j + 1]; ryy[j] = ryy[j + 1]; rxy[j] = rxy[j + 1];
    }
    rx[5] = hx; ry[5] = hy; rxx[5] = hxx; ryy[5] = hyy; rxy[5] = hxy;

    // publish next row to the other LDS buffer; single barrier handles
    // both RAW (next iter reads it) and WAR (this iter's reads are done)
    if (i < BAND_H + 5) { lx[cur ^ 1][c] = nx; ly[cur ^ 1][c] = ny; }
    __syncthreads();
  }

  // block reduction of SSIM partial sums -> per-image accumulator
#pragma unroll
  for (int off = 32; off; off >>= 1) acc += __shfl_down(acc, off);
  __shared__ float warr[8];
  int wave = threadIdx.x >> 6, lane = threadIdx.x & 63;
  if (lane == 0) warr[wave] = acc;
  __syncthreads();
  if (threadIdx.x == 0) {
    float s = 0.f;
#pragma unroll
    for (int w = 0; w < 8; ++w) s += warr[w];
    atomicAdd(&wsd[2 + img], (double)s);
  }
}

__global__ void finalize_kernel(const double* __restrict__ wsd,
                                float* __restrict__ out) {
  if (threadIdx.x == 0 && blockIdx.x == 0) {
    const double N = (double)N_IMG * (double)IMG_HW;   // 12582912
    double mae = wsd[0] / N;
    double mse = wsd[1] / N;
    double ssum = 0.0;
    for (int i = 0; i < N_IMG; ++i) ssum += wsd[2 + i];
    double smean = ssum / ((double)OUT_W * (double)OUT_H * (double)N_IMG);
    double ssim_loss = 1.0 - smean;
    double total = 1.0 * mae + 0.5 * mse + 0.2 * ssim_loss;
    out[0] = (float)total;
    out[1] = (float)mae;
    out[2] = (float)mse;
    out[3] = (float)ssim_loss;
  }
}

extern "C" void kernel_launch(void* const* d_in, const int* in_sizes, int n_in,
                              void* d_out, int out_size, void* d_ws,
                              size_t ws_size, hipStream_t stream) {
  const float* yp = (const float*)d_in[0];
  const float* yt = (const float*)d_in[1];
  const float* mk = (const float*)d_in[2];
  float* out = (float*)d_out;
  double* wsd = (double*)d_ws;
  unsigned* wsu = (unsigned*)((char*)d_ws + 400);

  hipLaunchKernelGGL(init_ws, dim3(1), dim3(64), 0, stream, wsd, wsu);
  hipLaunchKernelGGL(stat_kernel, dim3(N_IMG * 16), dim3(256), 0, stream,
                     (const float4*)yp, (const float4*)yt, (const float4*)mk,
                     wsd, wsu);
  hipLaunchKernelGGL(ssim_kernel, dim3(N_IMG * N_BANDS), dim3(512), 0, stream,
                     yp, yt, mk, wsd, wsu);
  hipLaunchKernelGGL(finalize_kernel, dim3(1), dim3(64), 0, stream, wsd, out);
}

// Round 2
// 93.232 us; speedup vs baseline: 1.1333x; 1.1333x over previous
//
#include <hip/hip_runtime.h>
#include <math.h>

// Problem geometry
#define N_IMG   48          // B*C = 8*6
#define IMG_W   512
#define IMG_H   512
#define IMG_HW  (IMG_W*IMG_H)
#define OUT_W   506         // 512 - 6 (VALID 7x7)
#define OUT_H   506
#define BAND_H  46          // output rows per band; 46*11 = 506
#define N_BANDS 11
#define HALF_COLS 253       // output columns per half-block
#define K1C     0.01f
#define K2C     0.03f

// ws layout:
//   double wsd[0]     = sum |diff|
//   double wsd[1]     = sum diff^2
//   double wsd[2..49] = per-image SSIM sum
//   unsigned wsu[0..47]  (at byte offset 400) = per-image min (ordered-uint map)
//   unsigned wsu[48..95]                      = per-image max (ordered-uint map)

__device__ __forceinline__ unsigned fmap(float f) {
  unsigned u = __float_as_uint(f);
  return (u & 0x80000000u) ? ~u : (u | 0x80000000u);
}
__device__ __forceinline__ float funmap(unsigned u) {
  return (u & 0x80000000u) ? __uint_as_float(u & 0x7FFFFFFFu)
                           : __uint_as_float(~u);
}

__global__ void init_ws(double* wsd, unsigned* wsu) {
  int t = threadIdx.x;
  if (t < 50) wsd[t] = 0.0;
  if (t < 48) { wsu[t] = 0xFFFFFFFFu; wsu[48 + t] = 0u; }
}

// Pass 1: per-image min/max of y_true*mask, global sum|diff| and sum diff^2.
__global__ __launch_bounds__(256) void stat_kernel(
    const float4* __restrict__ p4, const float4* __restrict__ t4,
    const float4* __restrict__ m4, double* __restrict__ wsd,
    unsigned* __restrict__ wsu) {
  const int img = blockIdx.x >> 4;
  const int chunk = blockIdx.x & 15;
  const size_t base = (size_t)img * (IMG_HW / 4) + (size_t)chunk * (IMG_HW / 64);
  const int t = threadIdx.x;

  float s1 = 0.f, s2 = 0.f, mn = INFINITY, mx = -INFINITY;
#pragma unroll 4
  for (int k = 0; k < 16; ++k) {
    size_t idx = base + (size_t)k * 256 + t;
    float4 a = p4[idx], b = t4[idx], m = m4[idx];
    {
      float d = (a.x - b.x) * m.x, v = b.x * m.x;
      s1 += fabsf(d); s2 = fmaf(d, d, s2);
      mn = fminf(mn, v); mx = fmaxf(mx, v);
    }
    {
      float d = (a.y - b.y) * m.y, v = b.y * m.y;
      s1 += fabsf(d); s2 = fmaf(d, d, s2);
      mn = fminf(mn, v); mx = fmaxf(mx, v);
    }
    {
      float d = (a.z - b.z) * m.z, v = b.z * m.z;
      s1 += fabsf(d); s2 = fmaf(d, d, s2);
      mn = fminf(mn, v); mx = fmaxf(mx, v);
    }
    {
      float d = (a.w - b.w) * m.w, v = b.w * m.w;
      s1 += fabsf(d); s2 = fmaf(d, d, s2);
      mn = fminf(mn, v); mx = fmaxf(mx, v);
    }
  }

#pragma unroll
  for (int off = 32; off; off >>= 1) {
    s1 += __shfl_down(s1, off);
    s2 += __shfl_down(s2, off);
    mn = fminf(mn, __shfl_down(mn, off));
    mx = fmaxf(mx, __shfl_down(mx, off));
  }
  __shared__ float r1[4], r2[4], rmn[4], rmx[4];
  int wave = t >> 6, lane = t & 63;
  if (lane == 0) { r1[wave] = s1; r2[wave] = s2; rmn[wave] = mn; rmx[wave] = mx; }
  __syncthreads();
  if (t == 0) {
    float S1 = 0.f, S2 = 0.f, MN = INFINITY, MX = -INFINITY;
#pragma unroll
    for (int w = 0; w < 4; ++w) {
      S1 += r1[w]; S2 += r2[w];
      MN = fminf(MN, rmn[w]); MX = fmaxf(MX, rmx[w]);
    }
    atomicAdd(&wsd[0], (double)S1);
    atomicAdd(&wsd[1], (double)S2);
    atomicMin(&wsu[img], fmap(MN));
    atomicMax(&wsu[48 + img], fmap(MX));
  }
}

// Pass 2: SSIM. One block per (image, band, column-half): 48*11*2 = 1056
// blocks of 256 threads. Thread = output column within the half. Separable
// 7x7 box via LDS-staged rows (double-buffered) + a 6-deep register ring
// with STATIC slot indices (row loop unrolled by 6 -> ring shift is free).
// Raw-sum SSIM algebra: the 1/49^2 and 1/(49*48) normalizations cancel in
// the ratio, so C1,C2 are pre-scaled by 2401 and 2352.

#define SSIM_ROW(J, ROW, WARM, LAST)                                        \
  {                                                                          \
    float nx0 = 0.f, ny0 = 0.f, nx1 = 0.f, ny1 = 0.f;                        \
    const bool pf = !(LAST);                                                 \
    if (pf) {                                                                \
      size_t off = rowbase + (size_t)((ROW) + 1) * IMG_W + t;                \
      float m0 = mk[off];                                                    \
      nx0 = yp[off] * m0; ny0 = yt[off] * m0;                                \
      if (extra) {                                                           \
        size_t o2 = off + 256;                                               \
        float m1 = mk[o2];                                                   \
        nx1 = yp[o2] * m1; ny1 = yt[o2] * m1;                                \
      }                                                                      \
    }                                                                        \
    float hx = 0.f, hy = 0.f, hxx = 0.f, hyy = 0.f, hxy = 0.f;               \
    if (prod) {                                                              \
      _Pragma("unroll")                                                      \
      for (int jj = 0; jj < 7; ++jj) {                                       \
        float xv = lx[(J) & 1][t + jj], yv = ly[(J) & 1][t + jj];            \
        hx += xv; hy += yv;                                                  \
        hxx = fmaf(xv, xv, hxx);                                             \
        hyy = fmaf(yv, yv, hyy);                                             \
        hxy = fmaf(xv, yv, hxy);                                             \
      }                                                                      \
    }                                                                        \
    if (!(WARM)) {                                                           \
      float sx = vx_ + hx, sy = vy_ + hy;                                    \
      float sxx = vxx + hxx, syy = vyy + hyy, sxy = vxy + hxy;               \
      if (prod) {                                                            \
        float p = sx * sy;                                                   \
        float q = fmaf(sx, sx, sy * sy);                                     \
        float tt = sxx + syy;                                                \
        float A1 = fmaf(2.f, p, C1q);                                        \
        float A2 = fmaf(-2.f, p, fmaf(98.f, sxy, C2q));                      \
        float B1 = q + C1q;                                                  \
        float B2 = fmaf(49.f, tt, C2q - q);                                  \
        acc = fmaf(A1 * A2, __builtin_amdgcn_rcpf(B1 * B2), acc);            \
      }                                                                      \
      vx_ += hx - rx[(J)]; vy_ += hy - ry[(J)];                              \
      vxx += hxx - rxx[(J)]; vyy += hyy - ryy[(J)]; vxy += hxy - rxy[(J)];   \
    } else {                                                                 \
      vx_ += hx; vy_ += hy; vxx += hxx; vyy += hyy; vxy += hxy;              \
    }                                                                        \
    rx[(J)] = hx; ry[(J)] = hy;                                              \
    rxx[(J)] = hxx; ryy[(J)] = hyy; rxy[(J)] = hxy;                          \
    if (pf) {                                                                \
      lx[1 - ((J) & 1)][t] = nx0; ly[1 - ((J) & 1)][t] = ny0;                \
      if (extra) {                                                           \
        lx[1 - ((J) & 1)][t + 256] = nx1; ly[1 - ((J) & 1)][t + 256] = ny1;  \
      }                                                                      \
    }                                                                        \
    __syncthreads();                                                         \
  }

__global__ __launch_bounds__(256) void ssim_kernel(
    const float* __restrict__ yp, const float* __restrict__ yt,
    const float* __restrict__ mk, double* __restrict__ wsd,
    const unsigned* __restrict__ wsu) {
  const int bid = blockIdx.x;
  const int img = bid / (2 * N_BANDS);
  const int rem = bid % (2 * N_BANDS);
  const int band = rem >> 1;
  const int half = rem & 1;
  const int c0 = half * HALF_COLS;
  const int r0 = band * BAND_H;
  const size_t rowbase = (size_t)img * IMG_HW + (size_t)r0 * IMG_W + c0;
  const int t = threadIdx.x;
  const bool extra = (t < 3);          // staged cols 256..258 of this half
  const bool prod = (t < HALF_COLS);   // threads producing an output column

  const float d = funmap(wsu[48 + img]) - funmap(wsu[img]);
  const float C1q = (K1C * d) * (K1C * d) * 2401.0f;   // C1 * 49^2
  const float C2q = (K2C * d) * (K2C * d) * 2352.0f;   // C2 * 49*48

  __shared__ float lx[2][264];
  __shared__ float ly[2][264];

  float rx[6] = {0,0,0,0,0,0}, ry[6] = {0,0,0,0,0,0};
  float rxx[6] = {0,0,0,0,0,0}, ryy[6] = {0,0,0,0,0,0}, rxy[6] = {0,0,0,0,0,0};
  float vx_ = 0.f, vy_ = 0.f, vxx = 0.f, vyy = 0.f, vxy = 0.f;
  float acc = 0.f;

  // stage input row 0 into buffer 0
  {
    size_t off = rowbase + t;
    float m0 = mk[off];
    lx[0][t] = yp[off] * m0; ly[0][t] = yt[off] * m0;
    if (extra) {
      size_t o2 = off + 256;
      float m1 = mk[o2];
      lx[0][t + 256] = yp[o2] * m1; ly[0][t + 256] = yt[o2] * m1;
    }
  }
  __syncthreads();

  // warm-up rows 0..5 (ring slots 0..5, no output)
  SSIM_ROW(0, 0, true, false)
  SSIM_ROW(1, 1, true, false)
  SSIM_ROW(2, 2, true, false)
  SSIM_ROW(3, 3, true, false)
  SSIM_ROW(4, 4, true, false)
  SSIM_ROW(5, 5, true, false)

  // output rows: input rows 6..51, slot = row mod 6 (static per position)
  for (int g = 0; g < 8; ++g) {
    const int rbase = 6 + 6 * g;
    SSIM_ROW(0, rbase + 0, false, false)
    SSIM_ROW(1, rbase + 1, false, false)
    SSIM_ROW(2, rbase + 2, false, false)
    SSIM_ROW(3, rbase + 3, false, (rbase + 3) == 51)
    if (rbase + 4 < 52) SSIM_ROW(4, rbase + 4, false, false)
    if (rbase + 5 < 52) SSIM_ROW(5, rbase + 5, false, false)
  }

  // block reduction -> per-image accumulator
#pragma unroll
  for (int off = 32; off; off >>= 1) acc += __shfl_down(acc, off);
  __shared__ float warr[4];
  int wave = t >> 6, lane = t & 63;
  if (lane == 0) warr[wave] = acc;
  __syncthreads();
  if (t == 0) {
    float s = warr[0] + warr[1] + warr[2] + warr[3];
    atomicAdd(&wsd[2 + img], (double)s);
  }
}

__global__ void finalize_kernel(const double* __restrict__ wsd,
                                float* __restrict__ out) {
  if (threadIdx.x == 0 && blockIdx.x == 0) {
    const double N = (double)N_IMG * (double)IMG_HW;   // 12582912
    double mae = wsd[0] / N;
    double mse = wsd[1] / N;
    double ssum = 0.0;
    for (int i = 0; i < N_IMG; ++i) ssum += wsd[2 + i];
    double smean = ssum / ((double)OUT_W * (double)OUT_H * (double)N_IMG);
    double ssim_loss = 1.0 - smean;
    double total = 1.0 * mae + 0.5 * mse + 0.2 * ssim_loss;
    out[0] = (float)total;
    out[1] = (float)mae;
    out[2] = (float)mse;
    out[3] = (float)ssim_loss;
  }
}

extern "C" void kernel_launch(void* const* d_in, const int* in_sizes, int n_in,
                              void* d_out, int out_size, void* d_ws,
                              size_t ws_size, hipStream_t stream) {
  const float* yp = (const float*)d_in[0];
  const float* yt = (const float*)d_in[1];
  const float* mk = (const float*)d_in[2];
  float* out = (float*)d_out;
  double* wsd = (double*)d_ws;
  unsigned* wsu = (unsigned*)((char*)d_ws + 400);

  hipLaunchKernelGGL(init_ws, dim3(1), dim3(64), 0, stream, wsd, wsu);
  hipLaunchKernelGGL(stat_kernel, dim3(N_IMG * 16), dim3(256), 0, stream,
                     (const float4*)yp, (const float4*)yt, (const float4*)mk,
                     wsd, wsu);
  hipLaunchKernelGGL(ssim_kernel, dim3(N_IMG * N_BANDS * 2), dim3(256), 0,
                     stream, yp, yt, mk, wsd, wsu);
  hipLaunchKernelGGL(finalize_kernel, dim3(1), dim3(64), 0, stream, wsd, out);
}